// Round 4
// baseline (200.729 us; speedup 1.0000x reference)
//
#include <hip/hip_runtime.h>
#include <stdint.h>
#include <math.h>

// Forbid compiler-introduced FMA contraction: the eager-JAX reference has NO
// contraction on the pixel path (each op is a separate XLA executable).
// Explicit fmaf() calls below remain fused (used only where the reference's
// internally-jitted subgraphs really contract: uniform/normal transforms, exp).
#pragma clang fp contract(off)

// ---- round-to-round toggles -------------------------------------------------
#define PRNG_PARTITIONABLE 1   // modern JAX (>=0.5) default threefry scheme
#define EXP_CEPHES_FMA 1       // XLA:CPU llvm_ir_runtime Cephes exp (fma'd Horner)

namespace {

constexpr int WI = 2048;
constexpr int HI = 128;
constexpr int NB = 64;
constexpr int NPIX = NB * HI * WI;  // 16,777,216

struct BParams {
  float a11, a12, a21, a22, txt, tyt;   // geometric inverse-affine
  float wpi, wsW, wsH;                  // warp: wf*pi, ws*W, ws*H
  float s_ero, thr, nscale;
  float br, co, ca, sa;                 // lighting
  uint32_t nk0, nk1;                    // ks[14] noise key
  int gate_geo, gate_warp, gate_ero, gate_bin, gate_jpeg, gate_light;
};

__device__ __forceinline__ uint32_t rotl32(uint32_t v, int d) {
  return (v << d) | (v >> (32 - d));
}

// Exact JAX threefry2x32 (5 groups of 4 rounds, rotations [13,15,26,6]/[17,29,16,24])
__device__ void threefry(uint32_t k0, uint32_t k1, uint32_t x0, uint32_t x1,
                         uint32_t& o0, uint32_t& o1) {
  const uint32_t ks2 = k0 ^ k1 ^ 0x1BD11BDAu;
  x0 += k0; x1 += k1;
#define TF_R(r) { x0 += x1; x1 = rotl32(x1, (r)); x1 ^= x0; }
  TF_R(13) TF_R(15) TF_R(26) TF_R(6)
  x0 += k1;  x1 += ks2 + 1u;
  TF_R(17) TF_R(29) TF_R(16) TF_R(24)
  x0 += ks2; x1 += k0 + 2u;
  TF_R(13) TF_R(15) TF_R(26) TF_R(6)
  x0 += k0;  x1 += k1 + 3u;
  TF_R(17) TF_R(29) TF_R(16) TF_R(24)
  x0 += k1;  x1 += ks2 + 4u;
  TF_R(13) TF_R(15) TF_R(26) TF_R(6)
  x0 += ks2; x1 += k0 + 5u;
#undef TF_R
  o0 = x0; o1 = x1;
}

// legacy split helper: bits48[j], j<24 -> o0 of enc(j, j+24); else o1 of enc(j-24, j)
__device__ uint32_t bits48_orig(uint32_t j) {
  uint32_t a, b;
  if (j < 24u) { threefry(0u, 42u, j, j + 24u, a, b); return a; }
  threefry(0u, 42u, j - 24u, j, a, b); return b;
}

// ks[i] from split(key(42), 24); key(42) = (0, 42)
__device__ void derive_key(uint32_t i, uint32_t& k0, uint32_t& k1) {
#if PRNG_PARTITIONABLE
  threefry(0u, 42u, 0u, i, k0, k1);
#else
  k0 = bits48_orig(2u * i);
  k1 = bits48_orig(2u * i + 1u);
#endif
}

// random_bits(key, 32, shape) flat element idx of an array with n total elements
__device__ uint32_t rbits_n(uint32_t k0, uint32_t k1, uint32_t idx, uint32_t n) {
#if PRNG_PARTITIONABLE
  uint32_t a, b;
  threefry(k0, k1, 0u, idx, a, b);   // 64-bit iota (hi=0, lo=idx)
  return a ^ b;                      // 64->32 xor fold
#else
  const uint32_t half = n >> 1;
  uint32_t a, b;
  if (idx < half) { threefry(k0, k1, idx, idx + half, a, b); return a; }
  threefry(k0, k1, idx - half, idx, a, b); return b;
#endif
}

// jax uniform bit transform: (bits>>9)|0x3f800000 bitcast - 1.0  ->  [0,1)
__device__ __forceinline__ float bits_to_f01(uint32_t bits) {
  return __uint_as_float((bits >> 9) | 0x3f800000u) - 1.0f;
}

// exp replication (zoom). Standalone Exp op -> XLA:CPU Cephes rewrite; its
// MulAdd chain contracts within the op. |arg|<=0.1 so range reduction is exact.
__device__ float ref_expf(float x) {
#if EXP_CEPHES_FMA
  x = fminf(x, 88.3762626647950f);
  x = fmaxf(x, -88.3762626647949f);
  float fx = floorf(fmaf(x, 1.44269504088896341f, 0.5f));
  x = fmaf(-0.693359375f, fx, x);
  x = fmaf(2.12194440e-4f, fx, x);
  float z = __fmul_rn(x, x);
  float y = fmaf(1.9875691500e-4f, x, 1.3981999507e-3f);
  y = fmaf(y, x, 8.3334519073e-3f);
  y = fmaf(y, x, 4.1665795894e-2f);
  y = fmaf(y, x, 1.6666665459e-1f);
  y = fmaf(y, x, 5.0000001201e-1f);
  y = fmaf(y, z, x);
  y = __fadd_rn(y, 1.0f);
  int n = (int)fx;
  float sc = __int_as_float((uint32_t)(n + 127) << 23);
  return __fmul_rn(y, sc);
#else
  return expf(x);
#endif
}

// sin/cos via double precision, rounded: matches correctly-rounded glibc sinf/cosf
__device__ __forceinline__ float ref_sinf(float a) { return (float)sin((double)a); }
__device__ __forceinline__ float ref_cosf(float a) { return (float)cos((double)a); }

// XLA ErfInv (Giles) — inside the jitted normal(), so Horner contracts to fma.
__device__ float erfinv_ref(float x) {
  float w = -log1pf(-__fmul_rn(x, x));
  float p;
  if (w < 5.0f) {
    w = __fsub_rn(w, 2.5f);
    p = 2.81022636e-08f;
    p = fmaf(p, w, 3.43273939e-07f);
    p = fmaf(p, w, -3.5233877e-06f);
    p = fmaf(p, w, -4.39150654e-06f);
    p = fmaf(p, w, 0.00021858087f);
    p = fmaf(p, w, -0.00125372503f);
    p = fmaf(p, w, -0.00417768164f);
    p = fmaf(p, w, 0.246640727f);
    p = fmaf(p, w, 1.50140941f);
  } else {
    w = __fsub_rn(sqrtf(w), 3.0f);
    p = -0.000200214257f;
    p = fmaf(p, w, 0.000100950558f);
    p = fmaf(p, w, 0.00134934322f);
    p = fmaf(p, w, -0.00367342844f);
    p = fmaf(p, w, 0.00573950773f);
    p = fmaf(p, w, -0.0076224613f);
    p = fmaf(p, w, 0.00943887047f);
    p = fmaf(p, w, 1.00167406f);
    p = fmaf(p, w, 2.83297682f);
  }
  return __fmul_rn(p, x);
}

__device__ __forceinline__ int iclampi(int v, int lo, int hi) {
  return v < lo ? lo : (v > hi ? hi : v);
}

// constant-fill bilinear (geometric stage). EAGER numerics: lerp is
// mul, mul, add — NO fma.
__device__ float bilin_constfill(const float* __restrict__ img, float yin, float xin) {
  const float y0f = floorf(yin), x0f = floorf(xin);
  const int y0 = (int)y0f, x0 = (int)x0f;
  const int y1 = y0 + 1, x1 = x0 + 1;
  const float fy = __fsub_rn(yin, y0f);
  const float fx = __fsub_rn(xin, x0f);
  const bool yv0 = (y0 >= 0) & (y0 < HI);
  const bool yv1 = (y1 >= 0) & (y1 < HI);
  const bool xv0 = (x0 >= 0) & (x0 < WI);
  const bool xv1 = (x1 >= 0) & (x1 < WI);
  const int yc0 = iclampi(y0, 0, HI - 1) * WI;
  const int yc1 = iclampi(y1, 0, HI - 1) * WI;
  const int xc0 = iclampi(x0, 0, WI - 1);
  const int xc1 = iclampi(x1, 0, WI - 1);
  const float I00 = (yv0 & xv0) ? img[yc0 + xc0] : 0.0f;
  const float I01 = (yv0 & xv1) ? img[yc0 + xc1] : 0.0f;
  const float I10 = (yv1 & xv0) ? img[yc1 + xc0] : 0.0f;
  const float I11 = (yv1 & xv1) ? img[yc1 + xc1] : 0.0f;
  const float omfx = __fsub_rn(1.0f, fx);
  const float omfy = __fsub_rn(1.0f, fy);
  const float I0 = __fadd_rn(__fmul_rn(I00, omfx), __fmul_rn(I01, fx));
  const float I1 = __fadd_rn(__fmul_rn(I10, omfx), __fmul_rn(I11, fx));
  return __fadd_rn(__fmul_rn(I0, omfy), __fmul_rn(I1, fy));
}

// geometric coords, EAGER: x_in = (a11*x + a12*y) + txt  — mul,mul,add,add
__device__ float geo_at(const float* __restrict__ img, const BParams& p, float yf, float xf) {
  const float xin = __fadd_rn(__fadd_rn(__fmul_rn(p.a11, xf), __fmul_rn(p.a12, yf)), p.txt);
  const float yin = __fadd_rn(__fadd_rn(__fmul_rn(p.a21, xf), __fmul_rn(p.a22, yf)), p.tyt);
  return bilin_constfill(img, yin, xin);
}

// post-geometric image at integer coords (warp's source); identical bits to the
// reference's materialized intermediate because the exact op sequence is replayed.
__device__ float postgeo(const float* __restrict__ img, const BParams& p, int iy, int ix) {
  if (p.gate_geo) return geo_at(img, p, (float)iy, (float)ix);
  return img[iy * WI + ix];
}

__global__ __launch_bounds__(256) void deformer_kernel(const float* __restrict__ in,
                                                       float* __restrict__ out) {
  const int tid = threadIdx.x;
  const int gid = blockIdx.x * 256 + tid;
  const int x = gid & (WI - 1);
  const int y = (gid >> 11) & (HI - 1);
  const int b = gid >> 18;          // uniform per block (256 | 2048)

  __shared__ float sf[20];
  __shared__ BParams p;

  if (tid < 20) {
    uint32_t k0, k1;
    derive_key((uint32_t)tid, k0, k1);
    sf[tid] = bits_to_f01(rbits_n(k0, k1, (uint32_t)b, 64u));
  }
  __syncthreads();
  if (tid == 0) {
    // uniform(lo,hi) — internally jitted -> max(lo, fma(f, hi-lo, lo))
    float uz   = fmaxf(-0.1f,   fmaf(sf[0], 0.2f,   -0.1f));
    float zoom = ref_expf(uz);
    float tyv  = fmaxf(-6.4f,   fmaf(sf[1], 12.8f,  -6.4f));
    float txv  = fmaxf(-102.4f, fmaf(sf[2], 102.4f, -102.4f));
    float shx  = fmaxf(-0.1f,   fmaf(sf[3], 0.2f,   -0.1f));
    float shy  = fmaxf(-0.1f,   fmaf(sf[4], 0.2f,   -0.1f));
    p.a11 = __fadd_rn(zoom, shx);
    p.a12 = shx;
    p.a21 = shy;
    p.a22 = __fadd_rn(zoom, shy);
    float om = __fsub_rn(1.0f, p.a22);
    // eager: cy*(1-a22) evaluated (twice, identically) as plain mul; adds separate
    float cyom = __fmul_rn(64.0f, om);
    p.txt = __fadd_rn(cyom, txv);
    p.tyt = __fadd_rn(cyom, tyv);
    p.gate_geo = sf[5] < 0.8f;

    float ws = __fmul_rn(sf[6], 0.02f);
    float wf = fmaxf(0.5f, fmaf(sf[7], 1.5f, 0.5f));
    p.wpi = __fmul_rn(wf, 3.14159274101257324219f);  // f32(pi)
    p.wsW = __fmul_rn(ws, 2048.0f);
    p.wsH = __fmul_rn(ws, 128.0f);
    p.gate_warp = sf[8] < 0.25f;

    p.s_ero = __fmul_rn(sf[9], 0.5f);
    p.gate_ero = sf[10] < 0.25f;

    p.thr = fmaxf(0.3f, fmaf(sf[11], 0.39999997615814208984f /* 0.7f-0.3f */, 0.3f));
    p.gate_bin = sf[12] < 0.25f;

    float q = fmaxf(30.0f, fmaf(sf[13], 60.0f, 30.0f));
    p.nscale = __fmul_rn(__fdiv_rn(__fsub_rn(100.0f, q), 100.0f), 0.1f);
    derive_key(14u, p.nk0, p.nk1);
    p.gate_jpeg = sf[15] < 0.125f;

    p.br = fmaxf(-0.2f, fmaf(sf[16], 0.4f, -0.2f));
    p.co = fmaxf(0.8f, fmaf(sf[17], 0.40000003576278686523f /* 1.2f-0.8f */, 0.8f));
    float ang = fmaxf(0.0f, __fmul_rn(sf[18], 6.28318548202514648438f)); // f32(2pi)
    p.ca = ref_cosf(ang);
    p.sa = ref_sinf(ang);
    p.gate_light = sf[19] < 0.25f;
  }
  __syncthreads();

  const float* img = in + ((size_t)b << 18);
  const float xf = (float)x, yf = (float)y;
  float v;

  if (p.gate_warp) {
    // EAGER: disp_x = (ws*W)*sin((wf*pi)*y/H); nx = clip(x + disp_x, ...)
    //        disp_y = ((ws*H)*sin((wf*pi)*x/W))*0.3 — all separate mul/add ops
    const float argx = __fdiv_rn(__fmul_rn(p.wpi, yf), 128.0f);
    const float argy = __fdiv_rn(__fmul_rn(p.wpi, xf), 2048.0f);
    const float dx = __fmul_rn(p.wsW, ref_sinf(argx));
    const float dy = __fmul_rn(__fmul_rn(p.wsH, ref_sinf(argy)), 0.3f);
    const float nx = fminf(fmaxf(__fadd_rn(xf, dx), 0.0f), (float)(2048.0 - 1.001));
    const float ny = fminf(fmaxf(__fadd_rn(yf, dy), 0.0f), (float)(128.0 - 1.001));
    const float y0f = floorf(ny), x0f = floorf(nx);
    const int y0 = (int)y0f, x0 = (int)x0f;
    const int y1 = min(y0 + 1, HI - 1), x1 = min(x0 + 1, WI - 1);
    const float fy = __fsub_rn(ny, y0f), fx = __fsub_rn(nx, x0f);
    const float I00 = postgeo(img, p, y0, x0);
    const float I01 = postgeo(img, p, y0, x1);
    const float I10 = postgeo(img, p, y1, x0);
    const float I11 = postgeo(img, p, y1, x1);
    const float omfx = __fsub_rn(1.0f, fx), omfy = __fsub_rn(1.0f, fy);
    const float I0 = __fadd_rn(__fmul_rn(I00, omfx), __fmul_rn(I01, fx));
    const float I1 = __fadd_rn(__fmul_rn(I10, omfx), __fmul_rn(I11, fx));
    v = __fadd_rn(__fmul_rn(I0, omfy), __fmul_rn(I1, fy));
  } else if (p.gate_geo) {
    v = geo_at(img, p, yf, xf);
  } else {
    v = img[(y << 11) + x];
  }

  if (p.gate_ero) {
    // eager: e = x-1; x*(1-s) + e*s  — mul, mul, add
    const float e = __fsub_rn(v, 1.0f);
    v = __fadd_rn(__fmul_rn(v, __fsub_rn(1.0f, p.s_ero)), __fmul_rn(e, p.s_ero));
  }
  if (p.gate_bin) {
    v = (v > p.thr) ? 1.0f : 0.0f;
  }
  if (p.gate_jpeg) {
    // noise[b, y/8, x/8, (y%8)*8 + x%8] from normal(ks[14], (64,16,256,64))
    const uint32_t idx =
        (uint32_t)((((b * 16 + (y >> 3)) * 256 + (x >> 3)) << 6) | ((y & 7) * 8 + (x & 7)));
    const uint32_t bits = rbits_n(p.nk0, p.nk1, idx, (uint32_t)NPIX);
    const float f = bits_to_f01(bits);
    const float lo = __uint_as_float(0xBF7FFFFFu);          // nextafter(-1,0)
    const float uu = fmaxf(lo, fmaf(f, 2.0f, lo));          // inside jitted normal()
    const float nrm = __fmul_rn(1.41421356237f, erfinv_ref(uu));
    // eager: m = normal*scale (mul); quant = blocked + m (add)
    v = __fadd_rn(v, __fmul_rn(nrm, p.nscale));
  }
  if (p.gate_light) {
    // eager linspace: xl = iota*delta + start (mul, add)
    const float xl = __fadd_rn(__fmul_rn(xf, 2.0f / 2047.0f), -1.0f);
    const float yl = __fadd_rn(__fmul_rn(yf, 2.0f / 127.0f), -1.0f);
    const float grad = __fadd_rn(__fmul_rn(p.ca, xl), __fmul_rn(p.sa, yl));
    const float bf = __fmul_rn(p.br, grad);
    // eager: ((x-0.5)*co + 0.5) + bf
    v = __fadd_rn(__fadd_rn(__fmul_rn(__fsub_rn(v, 0.5f), p.co), 0.5f), bf);
  }
  out[gid] = fminf(fmaxf(v, 0.0f), 1.0f);
}

}  // namespace

extern "C" void kernel_launch(void* const* d_in, const int* in_sizes, int n_in,
                              void* d_out, int out_size, void* d_ws, size_t ws_size,
                              hipStream_t stream) {
  (void)in_sizes; (void)n_in; (void)d_ws; (void)ws_size; (void)out_size;
  const float* in = (const float*)d_in[0];
  float* out = (float*)d_out;
  hipLaunchKernelGGL(deformer_kernel, dim3(NPIX / 256), dim3(256), 0, stream, in, out);
}